// Round 3
// baseline (753.561 us; speedup 1.0000x reference)
//
#include <hip/hip_runtime.h>

// B=2, T=2048, C=2048, H=32, KVH=8, HD=64, N_REP=4.
// Inputs fp32 (reference dtype), output fp32.
// Pipeline: cast x -> bf16; transpose-cast W -> bf16; fused QKV GEMM (+RoPE, +V^T store);
// flash attn (16x16x32 MFMA only, LDS-bounced P); out-proj GEMM (fp32 store).

typedef short short8 __attribute__((ext_vector_type(8)));
typedef float f32x4  __attribute__((ext_vector_type(4)));

__device__ __forceinline__ unsigned short f2bf(float x) {
  union { float f; unsigned u; } v; v.f = x;
  unsigned r = v.u + 0x7FFFu + ((v.u >> 16) & 1u);
  return (unsigned short)(r >> 16);
}

// ---------------- cast x (fp32 -> bf16), 4 elems/thread ----------------
__global__ __launch_bounds__(256) void cast_x_kernel(const float* __restrict__ in,
                                                     unsigned short* __restrict__ out, int n4) {
  int i = blockIdx.x * 256 + threadIdx.x;
  if (i >= n4) return;
  float4 v = ((const float4*)in)[i];
  ushort4 o; o.x = f2bf(v.x); o.y = f2bf(v.y); o.z = f2bf(v.z); o.w = f2bf(v.w);
  ((ushort4*)out)[i] = o;
}

// ------------- W[K=2048][N] fp32 -> Wt[N][2048] bf16 (tiled transpose-cast) -------------
__global__ __launch_bounds__(256) void transpose_cast(const float* __restrict__ W,
                                                      unsigned short* __restrict__ Wt,
                                                      int Ncols) {
  __shared__ float tile[32][33];
  const int nt = blockIdx.x, kt = blockIdx.y;
  const int lr = threadIdx.x >> 5, lc = threadIdx.x & 31;
  #pragma unroll
  for (int p = 0; p < 4; ++p) {
    int row = kt * 32 + lr + p * 8;
    tile[lr + p * 8][lc] = W[(size_t)row * Ncols + nt * 32 + lc];
  }
  __syncthreads();
  #pragma unroll
  for (int p = 0; p < 4; ++p) {
    int n = nt * 32 + lr + p * 8;
    Wt[(size_t)n * 2048 + kt * 32 + lc] = f2bf(tile[lc][lr + p * 8]);
  }
}

// ---------------- 128x128-tile bf16 GEMM, C = A[M][2048] x Wt[N][2048]^T ----------------
// kind==0: fp32 store to outP (out-projection)
// kind==1: QKV epilogue: cols<2048 -> Q (+RoPE); 2048..2559 -> K (+RoPE); 2560..3071 -> V^T store
__global__ __launch_bounds__(256) void gemm128(const unsigned short* __restrict__ A,
                                               const unsigned short* __restrict__ Wt,
                                               const float* __restrict__ freq,
                                               float* __restrict__ outP,
                                               unsigned short* __restrict__ Qb,
                                               unsigned short* __restrict__ Kb,
                                               unsigned short* __restrict__ Vt,
                                               int kind) {
  __shared__ __align__(16) unsigned short As[128 * 32];
  __shared__ __align__(16) unsigned short Bs[128 * 32];
  const int tid = threadIdx.x;
  const int lane = tid & 63;
  const int wave = tid >> 6;
  const int mb = blockIdx.x, nb = blockIdx.y;
  const int m0w = (wave >> 1) * 64, n0w = (wave & 1) * 64;

  f32x4 acc[4][4];
  #pragma unroll
  for (int i = 0; i < 4; ++i)
    #pragma unroll
    for (int j = 0; j < 4; ++j)
      #pragma unroll
      for (int t = 0; t < 4; ++t) acc[i][j][t] = 0.f;

  const int ca = tid, cb = tid + 256;          // 512 16B chunks per 128x32 tile
  const int rA0 = ca >> 2, wA0 = ca & 3;
  const int rA1 = cb >> 2, wA1 = cb & 3;

  for (int k0 = 0; k0 < 2048; k0 += 32) {
    short8 a0 = *(const short8*)&A [(size_t)(mb * 128 + rA0) * 2048 + k0 + wA0 * 8];
    short8 a1 = *(const short8*)&A [(size_t)(mb * 128 + rA1) * 2048 + k0 + wA1 * 8];
    short8 b0 = *(const short8*)&Wt[(size_t)(nb * 128 + rA0) * 2048 + k0 + wA0 * 8];
    short8 b1 = *(const short8*)&Wt[(size_t)(nb * 128 + rA1) * 2048 + k0 + wA1 * 8];
    __syncthreads();
    *(short8*)&As[ca * 8] = a0;  *(short8*)&As[cb * 8] = a1;
    *(short8*)&Bs[ca * 8] = b0;  *(short8*)&Bs[cb * 8] = b1;
    __syncthreads();
    short8 af[4], bfr[4];
    #pragma unroll
    for (int i = 0; i < 4; ++i) {
      af[i]  = *(const short8*)&As[(m0w + i * 16 + (lane & 15)) * 32 + (lane >> 4) * 8];
      bfr[i] = *(const short8*)&Bs[(n0w + i * 16 + (lane & 15)) * 32 + (lane >> 4) * 8];
    }
    #pragma unroll
    for (int i = 0; i < 4; ++i)
      #pragma unroll
      for (int j = 0; j < 4; ++j)
        acc[i][j] = __builtin_amdgcn_mfma_f32_16x16x32_bf16(af[i], bfr[j], acc[i][j], 0, 0, 0);
  }

  // C frag: row = (lane>>4)*4 + t, col = lane&15 (guide-verified m89/m91)
  const int colbase = n0w + (lane & 15);
  const int rowbase = mb * 128 + m0w + (lane >> 4) * 4;
  if (kind == 0) {
    #pragma unroll
    for (int i = 0; i < 4; ++i)
      #pragma unroll
      for (int j = 0; j < 4; ++j) {
        int col = nb * 128 + colbase + j * 16;
        #pragma unroll
        for (int t = 0; t < 4; ++t)
          outP[(size_t)(rowbase + i * 16 + t) * 2048 + col] = acc[i][j][t];
      }
  } else {
    #pragma unroll
    for (int i = 0; i < 4; ++i) {
      #pragma unroll
      for (int j = 0; j < 4; ++j) {
        int ncolg = nb * 128 + colbase + j * 16;   // 16-aligned groups: region is wave-uniform
        f32x4 v = acc[i][j];
        if (ncolg < 2560) {                        // Q or K: RoPE
          float pv[4];
          #pragma unroll
          for (int t = 0; t < 4; ++t) pv[t] = __shfl_xor(v[t], 1);
          const int ii = (ncolg & 63) >> 1;
          const bool evn = (ncolg & 1) == 0;
          #pragma unroll
          for (int t = 0; t < 4; ++t) {
            int gm = rowbase + i * 16 + t;
            int token = gm & 2047;
            float cc = freq[(token * 32 + ii) * 2];
            float ss = freq[(token * 32 + ii) * 2 + 1];
            float o = evn ? (v[t] * cc - pv[t] * ss) : (v[t] * cc + pv[t] * ss);
            if (ncolg < 2048) Qb[(size_t)gm * 2048 + ncolg] = f2bf(o);
            else              Kb[(size_t)gm * 512 + (ncolg - 2048)] = f2bf(o);
          }
        } else {                                   // V: transposed store Vt[b][kvh][d][token]
          int vc = ncolg - 2560;
          int kvh = vc >> 6, d = vc & 63;
          int gm0 = rowbase + i * 16;
          int bb = gm0 >> 11, token0 = gm0 & 2047;
          ushort4 pk;
          pk.x = f2bf(v[0]); pk.y = f2bf(v[1]); pk.z = f2bf(v[2]); pk.w = f2bf(v[3]);
          *(ushort4*)&Vt[((size_t)((bb * 8 + kvh) * 64 + d)) * 2048 + token0] = pk;
        }
      }
    }
  }
}

// -------- flash attention, 16x16x32 MFMA only. Per wave: 16 q-rows. --------
// S^T = K·Q^T  (A=K[kv][d]-contig, B=Q[q][d]-contig, C: col=q=lane&15, row kv_local=4g+t)
// P bounced via LDS [q][kv] -> exact verified B-operand pattern.
// O^T = V^T·P^T (A=Vt[d][token]-contig), C: col=q, row d_local=4g+t.
__global__ __launch_bounds__(256) void attn_kernel(const unsigned short* __restrict__ Qb,
                                                   const unsigned short* __restrict__ Kb,
                                                   const unsigned short* __restrict__ Vt,
                                                   unsigned short* __restrict__ AO) {
  __shared__ unsigned short P_lds[4][16][32];
  const int lane = threadIdx.x & 63;
  const int wave = threadIdx.x >> 6;
  const int qc = blockIdx.x, h = blockIdx.y, b = blockIdx.z;
  const int kvh = h >> 2;
  const int q0 = qc * 64 + wave * 16;
  const int ql = lane & 15, g = lane >> 4;

  const unsigned short* qrow = Qb + (size_t)(b * 2048 + q0 + ql) * 2048 + h * 64;
  short8 qf[2];
  #pragma unroll
  for (int s = 0; s < 2; ++s) qf[s] = *(const short8*)(qrow + s * 32 + g * 8);

  const unsigned short* kbase = Kb + (size_t)(b * 2048) * 512 + kvh * 64;
  const unsigned short* vbase = Vt + (size_t)((b * 8 + kvh) * 64) * 2048;

  f32x4 oacc[4];
  #pragma unroll
  for (int dt = 0; dt < 4; ++dt)
    #pragma unroll
    for (int t = 0; t < 4; ++t) oacc[dt][t] = 0.f;
  float mrun = -1e30f, lrun = 0.f;

  const int nkb = (q0 >> 5) + 1;
  for (int kb = 0; kb < nkb; ++kb) {
    const int kv0 = kb * 32;
    f32x4 sacc[2];
    #pragma unroll
    for (int kt = 0; kt < 2; ++kt)
      #pragma unroll
      for (int t = 0; t < 4; ++t) sacc[kt][t] = 0.f;
    #pragma unroll
    for (int kt = 0; kt < 2; ++kt) {
      const unsigned short* krow = kbase + (size_t)(kv0 + kt * 16 + ql) * 512;
      #pragma unroll
      for (int s = 0; s < 2; ++s) {
        short8 kf = *(const short8*)(krow + s * 32 + g * 8);
        sacc[kt] = __builtin_amdgcn_mfma_f32_16x16x32_bf16(kf, qf[s], sacc[kt], 0, 0, 0);
      }
    }
    float p[2][4];
    #pragma unroll
    for (int kt = 0; kt < 2; ++kt)
      #pragma unroll
      for (int t = 0; t < 4; ++t) p[kt][t] = sacc[kt][t] * 0.125f;   // 1/sqrt(64)
    if (kb == nkb - 1) {
      #pragma unroll
      for (int kt = 0; kt < 2; ++kt)
        #pragma unroll
        for (int t = 0; t < 4; ++t) {
          int kv = kv0 + kt * 16 + 4 * g + t;
          if (kv > q0 + ql) p[kt][t] = -1e30f;
        }
    }
    float bm = p[0][0];
    #pragma unroll
    for (int kt = 0; kt < 2; ++kt)
      #pragma unroll
      for (int t = 0; t < 4; ++t) bm = fmaxf(bm, p[kt][t]);
    bm = fmaxf(bm, __shfl_xor(bm, 16));
    bm = fmaxf(bm, __shfl_xor(bm, 32));
    const float mn = fmaxf(mrun, bm);
    const float alpha = __expf(mrun - mn);
    float ps = 0.f;
    #pragma unroll
    for (int kt = 0; kt < 2; ++kt)
      #pragma unroll
      for (int t = 0; t < 4; ++t) { p[kt][t] = __expf(p[kt][t] - mn); ps += p[kt][t]; }
    ps += __shfl_xor(ps, 16);
    ps += __shfl_xor(ps, 32);
    lrun = lrun * alpha + ps;
    mrun = mn;
    #pragma unroll
    for (int dt = 0; dt < 4; ++dt)
      #pragma unroll
      for (int t = 0; t < 4; ++t) oacc[dt][t] *= alpha;

    #pragma unroll
    for (int kt = 0; kt < 2; ++kt)
      #pragma unroll
      for (int t = 0; t < 4; ++t)
        P_lds[wave][ql][kt * 16 + 4 * g + t] = f2bf(p[kt][t]);
    short8 pf = *(const short8*)&P_lds[wave][ql][g * 8];
    #pragma unroll
    for (int dt = 0; dt < 4; ++dt) {
      short8 vf = *(const short8*)(vbase + (size_t)(dt * 16 + ql) * 2048 + kv0 + g * 8);
      oacc[dt] = __builtin_amdgcn_mfma_f32_16x16x32_bf16(vf, pf, oacc[dt], 0, 0, 0);
    }
  }

  const float inv = 1.0f / lrun;
  unsigned short* ao = AO + (size_t)(b * 2048 + q0 + ql) * 2048 + h * 64;
  #pragma unroll
  for (int dt = 0; dt < 4; ++dt)
    #pragma unroll
    for (int t = 0; t < 4; ++t)
      ao[dt * 16 + 4 * g + t] = f2bf(oacc[dt][t] * inv);
}

extern "C" void kernel_launch(void* const* d_in, const int* in_sizes, int n_in,
                              void* d_out, int out_size, void* d_ws, size_t ws_size,
                              hipStream_t stream) {
  const float* x    = (const float*)d_in[0];   // fp32 (B,T,C)
  const float* freq = (const float*)d_in[1];   // fp32 (T,32,2)
  // d_in[2] mask (causal, handled analytically), d_in[3] window (zeros, unused by reference)
  const float* Wq = (const float*)d_in[4];
  const float* Wk = (const float*)d_in[5];
  const float* Wv = (const float*)d_in[6];
  const float* Wo = (const float*)d_in[7];
  float* out = (float*)d_out;                  // fp32 (B,T,C)

  char* ws = (char*)d_ws;
  unsigned short* xb   = (unsigned short*)(ws);             // [4096][2048] bf16, 16.78 MB
  unsigned short* Wqkv = (unsigned short*)(ws + 16777216);  // [3072][2048] bf16, 12.58 MB
  unsigned short* Qb   = (unsigned short*)(ws + 29360128);  // [4096][2048] bf16, 16.78 MB
  unsigned short* Kb   = (unsigned short*)(ws + 46137344);  // [4096][512]  bf16,  4.19 MB
  unsigned short* Vt   = (unsigned short*)(ws + 50331648);  // [2][8][64][2048]    4.19 MB
  unsigned short* AO   = xb;                                // alias: x dead after QKV GEMM
  unsigned short* Wot  = Wqkv;                              // alias: Wqkv dead after QKV GEMM
  // total footprint: 54525952 B = 52 MiB (same as round 1, which ran without fault)

  cast_x_kernel<<<8192, 256, 0, stream>>>(x, xb, 2097152);
  transpose_cast<<<dim3(64, 64), 256, 0, stream>>>(Wq, Wqkv, 2048);
  transpose_cast<<<dim3(16, 64), 256, 0, stream>>>(Wk, Wqkv + (size_t)2048 * 2048, 512);
  transpose_cast<<<dim3(16, 64), 256, 0, stream>>>(Wv, Wqkv + (size_t)2560 * 2048, 512);
  gemm128<<<dim3(32, 24), 256, 0, stream>>>(xb, Wqkv, freq, nullptr, Qb, Kb, Vt, 1);
  transpose_cast<<<dim3(64, 64), 256, 0, stream>>>(Wo, Wot, 2048);
  attn_kernel<<<dim3(32, 32, 2), 256, 0, stream>>>(Qb, Kb, Vt, AO);
  gemm128<<<dim3(32, 16), 256, 0, stream>>>(AO, Wot, freq, out, nullptr, nullptr, nullptr, 0);
}

// Round 4
// 459.842 us; speedup vs baseline: 1.6387x; 1.6387x over previous
//
#include <hip/hip_runtime.h>

// B=2, T=2048, C=2048, H=32, KVH=8, HD=64, N_REP=4. Inputs fp32, output fp32.
// cast x -> bf16; transpose-cast W; QKV GEMM (global_load_lds, +RoPE +Q-scale-fold, +V^T);
// flash attn (32q/wave, KVBLK=64, K-prefetch, defer-max, swizzled LDS P); out-proj GEMM.

typedef short short8 __attribute__((ext_vector_type(8)));
typedef float f32x4  __attribute__((ext_vector_type(4)));

#define QSCALE 0.18033688011112042f  /* 0.125 * log2(e): S' = log2e * (q.k/8) */

__device__ __forceinline__ unsigned short f2bf(float x) {
  union { float f; unsigned u; } v; v.f = x;
  unsigned r = v.u + 0x7FFFu + ((v.u >> 16) & 1u);
  return (unsigned short)(r >> 16);
}

#if __has_builtin(__builtin_amdgcn_exp2f)
#define EXP2(x) __builtin_amdgcn_exp2f(x)
#else
#define EXP2(x) exp2f(x)
#endif

__device__ __forceinline__ void gload16(const unsigned short* g, unsigned short* l) {
  __builtin_amdgcn_global_load_lds((const __attribute__((address_space(1))) void*)g,
                                   (__attribute__((address_space(3))) void*)l, 16, 0, 0);
}

// ---------------- cast x (fp32 -> bf16) ----------------
__global__ __launch_bounds__(256) void cast_x_kernel(const float* __restrict__ in,
                                                     unsigned short* __restrict__ out, int n4) {
  int i = blockIdx.x * 256 + threadIdx.x;
  if (i >= n4) return;
  float4 v = ((const float4*)in)[i];
  ushort4 o; o.x = f2bf(v.x); o.y = f2bf(v.y); o.z = f2bf(v.z); o.w = f2bf(v.w);
  ((ushort4*)out)[i] = o;
}

// ------------- W[K=2048][N] fp32 -> Wt[N][2048] bf16 -------------
__global__ __launch_bounds__(256) void transpose_cast(const float* __restrict__ W,
                                                      unsigned short* __restrict__ Wt,
                                                      int Ncols) {
  __shared__ float tile[32][33];
  const int nt = blockIdx.x, kt = blockIdx.y;
  const int lr = threadIdx.x >> 5, lc = threadIdx.x & 31;
  #pragma unroll
  for (int p = 0; p < 4; ++p) {
    int row = kt * 32 + lr + p * 8;
    tile[lr + p * 8][lc] = W[(size_t)row * Ncols + nt * 32 + lc];
  }
  __syncthreads();
  #pragma unroll
  for (int p = 0; p < 4; ++p) {
    int n = nt * 32 + lr + p * 8;
    Wt[(size_t)n * 2048 + kt * 32 + lc] = f2bf(tile[lc][lr + p * 8]);
  }
}

// ---------------- 128x128-tile bf16 GEMM via global_load_lds ----------------
__global__ __launch_bounds__(256) void gemm128(const unsigned short* __restrict__ A,
                                               const unsigned short* __restrict__ Wt,
                                               const float* __restrict__ freq,
                                               float* __restrict__ outP,
                                               unsigned short* __restrict__ Qb,
                                               unsigned short* __restrict__ Kb,
                                               unsigned short* __restrict__ Vt,
                                               int kind) {
  __shared__ __align__(16) unsigned short As[128 * 32];
  __shared__ __align__(16) unsigned short Bs[128 * 32];
  const int tid = threadIdx.x;
  const int lane = tid & 63;
  const int wave = tid >> 6;
  const int mb = blockIdx.x, nb = blockIdx.y;
  const int m0w = (wave >> 1) * 64, n0w = (wave & 1) * 64;

  f32x4 acc[4][4];
  #pragma unroll
  for (int i = 0; i < 4; ++i)
    #pragma unroll
    for (int j = 0; j < 4; ++j)
      #pragma unroll
      for (int t = 0; t < 4; ++t) acc[i][j][t] = 0.f;

  const int ca = tid, cb = tid + 256;
  const size_t aoff0 = (size_t)(mb * 128 + (ca >> 2)) * 2048 + (ca & 3) * 8;
  const size_t aoff1 = (size_t)(mb * 128 + (cb >> 2)) * 2048 + (cb & 3) * 8;
  const size_t boff0 = (size_t)(nb * 128 + (ca >> 2)) * 2048 + (ca & 3) * 8;
  const size_t boff1 = (size_t)(nb * 128 + (cb >> 2)) * 2048 + (cb & 3) * 8;

  for (int k0 = 0; k0 < 2048; k0 += 32) {
    __syncthreads();
    gload16(A + aoff0 + k0, &As[ca * 8]);
    gload16(A + aoff1 + k0, &As[cb * 8]);
    gload16(Wt + boff0 + k0, &Bs[ca * 8]);
    gload16(Wt + boff1 + k0, &Bs[cb * 8]);
    __syncthreads();
    short8 af[4], bfr[4];
    #pragma unroll
    for (int i = 0; i < 4; ++i) {
      af[i]  = *(const short8*)&As[(m0w + i * 16 + (lane & 15)) * 32 + (lane >> 4) * 8];
      bfr[i] = *(const short8*)&Bs[(n0w + i * 16 + (lane & 15)) * 32 + (lane >> 4) * 8];
    }
    #pragma unroll
    for (int i = 0; i < 4; ++i)
      #pragma unroll
      for (int j = 0; j < 4; ++j)
        acc[i][j] = __builtin_amdgcn_mfma_f32_16x16x32_bf16(af[i], bfr[j], acc[i][j], 0, 0, 0);
  }

  // C frag: row = (lane>>4)*4 + t, col = lane&15
  const int colbase = n0w + (lane & 15);
  const int rowbase = mb * 128 + m0w + (lane >> 4) * 4;
  if (kind == 0) {
    #pragma unroll
    for (int i = 0; i < 4; ++i)
      #pragma unroll
      for (int j = 0; j < 4; ++j) {
        int col = nb * 128 + colbase + j * 16;
        #pragma unroll
        for (int t = 0; t < 4; ++t)
          outP[(size_t)(rowbase + i * 16 + t) * 2048 + col] = acc[i][j][t];
      }
  } else {
    #pragma unroll
    for (int i = 0; i < 4; ++i) {
      #pragma unroll
      for (int j = 0; j < 4; ++j) {
        int ncolg = nb * 128 + colbase + j * 16;
        f32x4 v = acc[i][j];
        if (ncolg < 2560) {                        // Q or K: RoPE
          float pv[4];
          #pragma unroll
          for (int t = 0; t < 4; ++t) pv[t] = __shfl_xor(v[t], 1);
          const int ii = (ncolg & 63) >> 1;
          const bool evn = (ncolg & 1) == 0;
          #pragma unroll
          for (int t = 0; t < 4; ++t) {
            int gm = rowbase + i * 16 + t;
            int token = gm & 2047;
            float cc = freq[(token * 32 + ii) * 2];
            float ss = freq[(token * 32 + ii) * 2 + 1];
            float o = evn ? (v[t] * cc - pv[t] * ss) : (v[t] * cc + pv[t] * ss);
            if (ncolg < 2048) Qb[(size_t)gm * 2048 + ncolg] = f2bf(o * QSCALE);
            else              Kb[(size_t)gm * 512 + (ncolg - 2048)] = f2bf(o);
          }
        } else {                                   // V: transposed store Vt[b][kvh][d][token]
          int vc = ncolg - 2560;
          int kvh = vc >> 6, d = vc & 63;
          int gm0 = rowbase + i * 16;
          int bb = gm0 >> 11, token0 = gm0 & 2047;
          ushort4 pk;
          pk.x = f2bf(v[0]); pk.y = f2bf(v[1]); pk.z = f2bf(v[2]); pk.w = f2bf(v[3]);
          *(ushort4*)&Vt[((size_t)((bb * 8 + kvh) * 64 + d)) * 2048 + token0] = pk;
        }
      }
    }
  }
}

// -------- flash attention v2: 32 q/wave (qi 0..1), KVBLK=64, K-prefetch, defer-max --------
// S^T = K·Q^T : sacc[kt][qi], C col=q=lane&15, row kv_local=4g+t.  (Q pre-scaled by QSCALE)
// P -> swizzled per-wave LDS -> B frag.  O^T = V^T·P^T : oacc[dt][qi].
__global__ __launch_bounds__(256) void attn_kernel(const unsigned short* __restrict__ Qb,
                                                   const unsigned short* __restrict__ Kb,
                                                   const unsigned short* __restrict__ Vt,
                                                   unsigned short* __restrict__ AO) {
  __shared__ __align__(16) char P_raw[4][4096];   // per-wave [qi][16 q][64 kv] bf16, XOR-swizzled
  const int lane = threadIdx.x & 63;
  const int wave = threadIdx.x >> 6;
  const int qcb = blockIdx.x, h = blockIdx.y, b = blockIdx.z;
  const int kvh = h >> 2;
  const int ql = lane & 15, g = lane >> 4;
  const int swz = (ql & 7) << 4;
  char* pbase = P_raw[wave];
  const unsigned short* kbase = Kb + (size_t)(b * 2048) * 512 + kvh * 64;
  const unsigned short* vbase = Vt + (size_t)((b * 8 + kvh) * 64) * 2048;

  for (int pass = 0; pass < 2; ++pass) {
    const int q0w = (pass ? (15 - qcb) : qcb) * 128 + wave * 32;  // balanced pair
    short8 qf[2][2];
    #pragma unroll
    for (int qi = 0; qi < 2; ++qi)
      #pragma unroll
      for (int s = 0; s < 2; ++s)
        qf[qi][s] = *(const short8*)(Qb + (size_t)(b * 2048 + q0w + qi * 16 + ql) * 2048 +
                                     h * 64 + s * 32 + g * 8);
    f32x4 oacc[4][2];
    #pragma unroll
    for (int dt = 0; dt < 4; ++dt)
      #pragma unroll
      for (int qi = 0; qi < 2; ++qi)
        #pragma unroll
        for (int t = 0; t < 4; ++t) oacc[dt][qi][t] = 0.f;
    float m0 = -3e38f, m1 = -3e38f, l0 = 0.f, l1 = 0.f;

    const int nkb = (q0w >> 6) + 1;
    short8 kf[4][2], kfn[4][2];
    #pragma unroll
    for (int kt = 0; kt < 4; ++kt)
      #pragma unroll
      for (int s = 0; s < 2; ++s)
        kf[kt][s] = *(const short8*)(kbase + (size_t)(kt * 16 + ql) * 512 + s * 32 + g * 8);

    for (int kb = 0; kb < nkb; ++kb) {
      const int kv0 = kb * 64;
      f32x4 sacc[4][2];
      #pragma unroll
      for (int kt = 0; kt < 4; ++kt)
        #pragma unroll
        for (int qi = 0; qi < 2; ++qi)
          #pragma unroll
          for (int t = 0; t < 4; ++t) sacc[kt][qi][t] = 0.f;
      #pragma unroll
      for (int kt = 0; kt < 4; ++kt)
        #pragma unroll
        for (int s = 0; s < 2; ++s)
          #pragma unroll
          for (int qi = 0; qi < 2; ++qi)
            sacc[kt][qi] = __builtin_amdgcn_mfma_f32_16x16x32_bf16(kf[kt][s], qf[qi][s],
                                                                   sacc[kt][qi], 0, 0, 0);
      if (kb + 1 < nkb) {           // prefetch next K tile (hidden under softmax+PV)
        #pragma unroll
        for (int kt = 0; kt < 4; ++kt)
          #pragma unroll
          for (int s = 0; s < 2; ++s)
            kfn[kt][s] = *(const short8*)(kbase + (size_t)(kv0 + 64 + kt * 16 + ql) * 512 +
                                          s * 32 + g * 8);
      }
      if (kb == nkb - 1) {          // causal mask on diagonal tile
        #pragma unroll
        for (int kt = 0; kt < 4; ++kt)
          #pragma unroll
          for (int qi = 0; qi < 2; ++qi)
            #pragma unroll
            for (int t = 0; t < 4; ++t) {
              int kv = kv0 + kt * 16 + 4 * g + t;
              if (kv > q0w + qi * 16 + ql) sacc[kt][qi][t] = -1e30f;
            }
      }
      float bm0 = sacc[0][0][0], bm1 = sacc[0][1][0];
      #pragma unroll
      for (int kt = 0; kt < 4; ++kt)
        #pragma unroll
        for (int t = 0; t < 4; ++t) {
          bm0 = fmaxf(bm0, sacc[kt][0][t]);
          bm1 = fmaxf(bm1, sacc[kt][1][t]);
        }
      bm0 = fmaxf(bm0, __shfl_xor(bm0, 16)); bm0 = fmaxf(bm0, __shfl_xor(bm0, 32));
      bm1 = fmaxf(bm1, __shfl_xor(bm1, 16)); bm1 = fmaxf(bm1, __shfl_xor(bm1, 32));
      if (!__all(bm0 <= m0 + 8.f && bm1 <= m1 + 8.f)) {   // defer-max (T13, log2 units)
        float mn0 = fmaxf(m0, bm0), mn1 = fmaxf(m1, bm1);
        float a0 = EXP2(m0 - mn0), a1 = EXP2(m1 - mn1);
        m0 = mn0; m1 = mn1; l0 *= a0; l1 *= a1;
        #pragma unroll
        for (int dt = 0; dt < 4; ++dt)
          #pragma unroll
          for (int t = 0; t < 4; ++t) { oacc[dt][0][t] *= a0; oacc[dt][1][t] *= a1; }
      }
      float ps0 = 0.f, ps1 = 0.f;
      #pragma unroll
      for (int kt = 0; kt < 4; ++kt)
        #pragma unroll
        for (int t = 0; t < 4; ++t) {
          float e0 = EXP2(sacc[kt][0][t] - m0); sacc[kt][0][t] = e0; ps0 += e0;
          float e1 = EXP2(sacc[kt][1][t] - m1); sacc[kt][1][t] = e1; ps1 += e1;
        }
      ps0 += __shfl_xor(ps0, 16); ps0 += __shfl_xor(ps0, 32);
      ps1 += __shfl_xor(ps1, 16); ps1 += __shfl_xor(ps1, 32);
      l0 += ps0; l1 += ps1;

      #pragma unroll
      for (int qi = 0; qi < 2; ++qi)
        #pragma unroll
        for (int kt = 0; kt < 4; ++kt) {
          uint2 w;
          w.x = (unsigned)f2bf(sacc[kt][qi][0]) | ((unsigned)f2bf(sacc[kt][qi][1]) << 16);
          w.y = (unsigned)f2bf(sacc[kt][qi][2]) | ((unsigned)f2bf(sacc[kt][qi][3]) << 16);
          *(uint2*)(pbase + qi * 2048 + ((ql * 128 + kt * 32 + g * 8) ^ swz)) = w;
        }
      short8 pf[2][2];
      #pragma unroll
      for (int qi = 0; qi < 2; ++qi)
        #pragma unroll
        for (int c = 0; c < 2; ++c)
          pf[qi][c] = *(const short8*)(pbase + qi * 2048 + ((ql * 128 + c * 64 + g * 16) ^ swz));
      #pragma unroll
      for (int dt = 0; dt < 4; ++dt)
        #pragma unroll
        for (int c = 0; c < 2; ++c) {
          short8 vf = *(const short8*)(vbase + (size_t)(dt * 16 + ql) * 2048 + kv0 + c * 32 + g * 8);
          #pragma unroll
          for (int qi = 0; qi < 2; ++qi)
            oacc[dt][qi] = __builtin_amdgcn_mfma_f32_16x16x32_bf16(vf, pf[qi][c],
                                                                   oacc[dt][qi], 0, 0, 0);
        }
      if (kb + 1 < nkb) {
        #pragma unroll
        for (int kt = 0; kt < 4; ++kt)
          #pragma unroll
          for (int s = 0; s < 2; ++s) kf[kt][s] = kfn[kt][s];
      }
    }

    const float inv0 = 1.f / l0, inv1 = 1.f / l1;
    #pragma unroll
    for (int qi = 0; qi < 2; ++qi) {
      const float inv = qi ? inv1 : inv0;
      unsigned short* ao = AO + (size_t)(b * 2048 + q0w + qi * 16 + ql) * 2048 + h * 64;
      #pragma unroll
      for (int dt = 0; dt < 4; ++dt) {
        ushort4 pk;
        pk.x = f2bf(oacc[dt][qi][0] * inv); pk.y = f2bf(oacc[dt][qi][1] * inv);
        pk.z = f2bf(oacc[dt][qi][2] * inv); pk.w = f2bf(oacc[dt][qi][3] * inv);
        *(ushort4*)&ao[dt * 16 + 4 * g] = pk;
      }
    }
  }
}

extern "C" void kernel_launch(void* const* d_in, const int* in_sizes, int n_in,
                              void* d_out, int out_size, void* d_ws, size_t ws_size,
                              hipStream_t stream) {
  const float* x    = (const float*)d_in[0];
  const float* freq = (const float*)d_in[1];
  const float* Wq = (const float*)d_in[4];
  const float* Wk = (const float*)d_in[5];
  const float* Wv = (const float*)d_in[6];
  const float* Wo = (const float*)d_in[7];
  float* out = (float*)d_out;

  char* ws = (char*)d_ws;
  unsigned short* xb   = (unsigned short*)(ws);             // [4096][2048] bf16, 16.78 MB
  unsigned short* Wqkv = (unsigned short*)(ws + 16777216);  // [3072][2048] bf16, 12.58 MB
  unsigned short* Qb   = (unsigned short*)(ws + 29360128);  // [4096][2048] bf16 (pre-scaled)
  unsigned short* Kb   = (unsigned short*)(ws + 46137344);  // [4096][512]  bf16
  unsigned short* Vt   = (unsigned short*)(ws + 50331648);  // [2][8][64][2048]
  unsigned short* AO   = xb;                                // alias: x dead after QKV GEMM
  unsigned short* Wot  = Wqkv;                              // alias: Wqkv dead after QKV GEMM

  cast_x_kernel<<<8192, 256, 0, stream>>>(x, xb, 2097152);
  transpose_cast<<<dim3(64, 64), 256, 0, stream>>>(Wq, Wqkv, 2048);
  transpose_cast<<<dim3(16, 64), 256, 0, stream>>>(Wk, Wqkv + (size_t)2048 * 2048, 512);
  transpose_cast<<<dim3(16, 64), 256, 0, stream>>>(Wv, Wqkv + (size_t)2560 * 2048, 512);
  gemm128<<<dim3(32, 24), 256, 0, stream>>>(xb, Wqkv, freq, nullptr, Qb, Kb, Vt, 1);
  transpose_cast<<<dim3(64, 64), 256, 0, stream>>>(Wo, Wot, 2048);
  attn_kernel<<<dim3(8, 32, 2), 256, 0, stream>>>(Qb, Kb, Vt, AO);
  gemm128<<<dim3(32, 16), 256, 0, stream>>>(AO, Wot, freq, out, nullptr, nullptr, nullptr, 0);
}

// Round 5
// 431.144 us; speedup vs baseline: 1.7478x; 1.0666x over previous
//
#include <hip/hip_runtime.h>

// B=2, T=2048, C=2048, H=32, KVH=8, HD=64, N_REP=4. Inputs fp32, output fp32.
// cast x -> bf16; transpose-cast W; QKV GEMM (global_load_lds, +RoPE +Q-scale-fold, +V^T);
// flash attn (32q/wave, KVBLK=64, K-prefetch, V-hoist, defer-max, swizzled LDS P,
// XCD-resident K/V); out-proj GEMM.

typedef short short8 __attribute__((ext_vector_type(8)));
typedef float f32x4  __attribute__((ext_vector_type(4)));

#define QSCALE 0.18033688011112042f  /* 0.125 * log2(e): S' = log2e * (q.k/8) */

__device__ __forceinline__ unsigned short f2bf(float x) {
  union { float f; unsigned u; } v; v.f = x;
  unsigned r = v.u + 0x7FFFu + ((v.u >> 16) & 1u);
  return (unsigned short)(r >> 16);
}

#if __has_builtin(__builtin_amdgcn_exp2f)
#define EXP2(x) __builtin_amdgcn_exp2f(x)
#else
#define EXP2(x) exp2f(x)
#endif

__device__ __forceinline__ void gload16(const unsigned short* g, unsigned short* l) {
  __builtin_amdgcn_global_load_lds((const __attribute__((address_space(1))) void*)g,
                                   (__attribute__((address_space(3))) void*)l, 16, 0, 0);
}

// ---------------- cast x (fp32 -> bf16) ----------------
__global__ __launch_bounds__(256) void cast_x_kernel(const float* __restrict__ in,
                                                     unsigned short* __restrict__ out, int n4) {
  int i = blockIdx.x * 256 + threadIdx.x;
  if (i >= n4) return;
  float4 v = ((const float4*)in)[i];
  ushort4 o; o.x = f2bf(v.x); o.y = f2bf(v.y); o.z = f2bf(v.z); o.w = f2bf(v.w);
  ((ushort4*)out)[i] = o;
}

// ------------- W[K=2048][N] fp32 -> Wt[N][2048] bf16 -------------
__global__ __launch_bounds__(256) void transpose_cast(const float* __restrict__ W,
                                                      unsigned short* __restrict__ Wt,
                                                      int Ncols) {
  __shared__ float tile[32][33];
  const int nt = blockIdx.x, kt = blockIdx.y;
  const int lr = threadIdx.x >> 5, lc = threadIdx.x & 31;
  #pragma unroll
  for (int p = 0; p < 4; ++p) {
    int row = kt * 32 + lr + p * 8;
    tile[lr + p * 8][lc] = W[(size_t)row * Ncols + nt * 32 + lc];
  }
  __syncthreads();
  #pragma unroll
  for (int p = 0; p < 4; ++p) {
    int n = nt * 32 + lr + p * 8;
    Wt[(size_t)n * 2048 + kt * 32 + lc] = f2bf(tile[lc][lr + p * 8]);
  }
}

// ---------------- 128x128-tile bf16 GEMM via global_load_lds ----------------
__global__ __launch_bounds__(256) void gemm128(const unsigned short* __restrict__ A,
                                               const unsigned short* __restrict__ Wt,
                                               const float* __restrict__ freq,
                                               float* __restrict__ outP,
                                               unsigned short* __restrict__ Qb,
                                               unsigned short* __restrict__ Kb,
                                               unsigned short* __restrict__ Vt,
                                               int kind) {
  __shared__ __align__(16) unsigned short As[128 * 32];
  __shared__ __align__(16) unsigned short Bs[128 * 32];
  const int tid = threadIdx.x;
  const int lane = tid & 63;
  const int wave = tid >> 6;
  const int mb = blockIdx.x, nb = blockIdx.y;
  const int m0w = (wave >> 1) * 64, n0w = (wave & 1) * 64;

  f32x4 acc[4][4];
  #pragma unroll
  for (int i = 0; i < 4; ++i)
    #pragma unroll
    for (int j = 0; j < 4; ++j)
      #pragma unroll
      for (int t = 0; t < 4; ++t) acc[i][j][t] = 0.f;

  const int ca = tid, cb = tid + 256;
  const size_t aoff0 = (size_t)(mb * 128 + (ca >> 2)) * 2048 + (ca & 3) * 8;
  const size_t aoff1 = (size_t)(mb * 128 + (cb >> 2)) * 2048 + (cb & 3) * 8;
  const size_t boff0 = (size_t)(nb * 128 + (ca >> 2)) * 2048 + (ca & 3) * 8;
  const size_t boff1 = (size_t)(nb * 128 + (cb >> 2)) * 2048 + (cb & 3) * 8;

  for (int k0 = 0; k0 < 2048; k0 += 32) {
    __syncthreads();
    gload16(A + aoff0 + k0, &As[ca * 8]);
    gload16(A + aoff1 + k0, &As[cb * 8]);
    gload16(Wt + boff0 + k0, &Bs[ca * 8]);
    gload16(Wt + boff1 + k0, &Bs[cb * 8]);
    __syncthreads();
    short8 af[4], bfr[4];
    #pragma unroll
    for (int i = 0; i < 4; ++i) {
      af[i]  = *(const short8*)&As[(m0w + i * 16 + (lane & 15)) * 32 + (lane >> 4) * 8];
      bfr[i] = *(const short8*)&Bs[(n0w + i * 16 + (lane & 15)) * 32 + (lane >> 4) * 8];
    }
    #pragma unroll
    for (int i = 0; i < 4; ++i)
      #pragma unroll
      for (int j = 0; j < 4; ++j)
        acc[i][j] = __builtin_amdgcn_mfma_f32_16x16x32_bf16(af[i], bfr[j], acc[i][j], 0, 0, 0);
  }

  // C frag: row = (lane>>4)*4 + t, col = lane&15
  const int colbase = n0w + (lane & 15);
  const int rowbase = mb * 128 + m0w + (lane >> 4) * 4;
  if (kind == 0) {
    #pragma unroll
    for (int i = 0; i < 4; ++i)
      #pragma unroll
      for (int j = 0; j < 4; ++j) {
        int col = nb * 128 + colbase + j * 16;
        #pragma unroll
        for (int t = 0; t < 4; ++t)
          outP[(size_t)(rowbase + i * 16 + t) * 2048 + col] = acc[i][j][t];
      }
  } else {
    #pragma unroll
    for (int i = 0; i < 4; ++i) {
      #pragma unroll
      for (int j = 0; j < 4; ++j) {
        int ncolg = nb * 128 + colbase + j * 16;
        f32x4 v = acc[i][j];
        if (ncolg < 2560) {                        // Q or K: RoPE
          float pv[4];
          #pragma unroll
          for (int t = 0; t < 4; ++t) pv[t] = __shfl_xor(v[t], 1);
          const int ii = (ncolg & 63) >> 1;
          const bool evn = (ncolg & 1) == 0;
          #pragma unroll
          for (int t = 0; t < 4; ++t) {
            int gm = rowbase + i * 16 + t;
            int token = gm & 2047;
            float cc = freq[(token * 32 + ii) * 2];
            float ss = freq[(token * 32 + ii) * 2 + 1];
            float o = evn ? (v[t] * cc - pv[t] * ss) : (v[t] * cc + pv[t] * ss);
            if (ncolg < 2048) Qb[(size_t)gm * 2048 + ncolg] = f2bf(o * QSCALE);
            else              Kb[(size_t)gm * 512 + (ncolg - 2048)] = f2bf(o);
          }
        } else {                                   // V: transposed store Vt[b][kvh][d][token]
          int vc = ncolg - 2560;
          int kvh = vc >> 6, d = vc & 63;
          int gm0 = rowbase + i * 16;
          int bb = gm0 >> 11, token0 = gm0 & 2047;
          ushort4 pk;
          pk.x = f2bf(v[0]); pk.y = f2bf(v[1]); pk.z = f2bf(v[2]); pk.w = f2bf(v[3]);
          *(ushort4*)&Vt[((size_t)((bb * 8 + kvh) * 64 + d)) * 2048 + token0] = pk;
        }
      }
    }
  }
}

// -------- flash attention v3: XCD-resident K/V, 32 q/wave, KVBLK=64, K-prefetch,
// V-hoist, defer-max, swizzled LDS P bounce, setprio around MFMA clusters --------
__global__ __launch_bounds__(256) void attn_kernel(const unsigned short* __restrict__ Qb,
                                                   const unsigned short* __restrict__ Kb,
                                                   const unsigned short* __restrict__ Vt,
                                                   unsigned short* __restrict__ AO) {
  __shared__ __align__(16) char P_raw[4][4096];   // per-wave [qi][16 q][64 kv] bf16, XOR-swizzled
  const int lane = threadIdx.x & 63;
  const int wave = threadIdx.x >> 6;
  // XCD-aware decode: blkid&7 == kvh -> all 32 blocks sharing one (b,kvh) K/V set (512 KB)
  // land on one XCD (presumed xcd = blkid % 8 round-robin); per-XCD working set = 1 MB < 4 MB L2.
  const int blkid = blockIdx.x;
  const int kvh = blkid & 7;
  const int sl  = blkid >> 3;
  const int b   = sl >> 5;
  const int ii_ = sl & 31;
  const int qcb = ii_ & 7;
  const int h   = kvh * 4 + (ii_ >> 3);
  const int ql = lane & 15, g = lane >> 4;
  const int swz = (ql & 7) << 4;
  char* pbase = P_raw[wave];
  const unsigned short* kbase = Kb + (size_t)(b * 2048) * 512 + kvh * 64;
  const unsigned short* vbase = Vt + (size_t)((b * 8 + kvh) * 64) * 2048;

  for (int pass = 0; pass < 2; ++pass) {
    const int q0w = (pass ? (15 - qcb) : qcb) * 128 + wave * 32;  // balanced pair
    short8 qf[2][2];
    #pragma unroll
    for (int qi = 0; qi < 2; ++qi)
      #pragma unroll
      for (int s = 0; s < 2; ++s)
        qf[qi][s] = *(const short8*)(Qb + (size_t)(b * 2048 + q0w + qi * 16 + ql) * 2048 +
                                     h * 64 + s * 32 + g * 8);
    f32x4 oacc[4][2];
    #pragma unroll
    for (int dt = 0; dt < 4; ++dt)
      #pragma unroll
      for (int qi = 0; qi < 2; ++qi)
        #pragma unroll
        for (int t = 0; t < 4; ++t) oacc[dt][qi][t] = 0.f;
    float m0 = -3e38f, m1 = -3e38f, l0 = 0.f, l1 = 0.f;

    const int nkb = (q0w >> 6) + 1;
    short8 kf[4][2], kfn[4][2];
    #pragma unroll
    for (int kt = 0; kt < 4; ++kt)
      #pragma unroll
      for (int s = 0; s < 2; ++s)
        kf[kt][s] = *(const short8*)(kbase + (size_t)(kt * 16 + ql) * 512 + s * 32 + g * 8);

    for (int kb = 0; kb < nkb; ++kb) {
      const int kv0 = kb * 64;
      f32x4 sacc[4][2];
      #pragma unroll
      for (int kt = 0; kt < 4; ++kt)
        #pragma unroll
        for (int qi = 0; qi < 2; ++qi)
          #pragma unroll
          for (int t = 0; t < 4; ++t) sacc[kt][qi][t] = 0.f;
      __builtin_amdgcn_s_setprio(1);
      #pragma unroll
      for (int kt = 0; kt < 4; ++kt)
        #pragma unroll
        for (int s = 0; s < 2; ++s)
          #pragma unroll
          for (int qi = 0; qi < 2; ++qi)
            sacc[kt][qi] = __builtin_amdgcn_mfma_f32_16x16x32_bf16(kf[kt][s], qf[qi][s],
                                                                   sacc[kt][qi], 0, 0, 0);
      __builtin_amdgcn_s_setprio(0);
      // hoist V loads: issued here, consumed after softmax (~400 cyc of cover)
      short8 vf[4][2];
      #pragma unroll
      for (int dt = 0; dt < 4; ++dt)
        #pragma unroll
        for (int c = 0; c < 2; ++c)
          vf[dt][c] = *(const short8*)(vbase + (size_t)(dt * 16 + ql) * 2048 + kv0 +
                                       c * 32 + g * 8);
      if (kb + 1 < nkb) {           // prefetch next K tile (hidden under softmax+PV)
        #pragma unroll
        for (int kt = 0; kt < 4; ++kt)
          #pragma unroll
          for (int s = 0; s < 2; ++s)
            kfn[kt][s] = *(const short8*)(kbase + (size_t)(kv0 + 64 + kt * 16 + ql) * 512 +
                                          s * 32 + g * 8);
      }
      if (kb == nkb - 1) {          // causal mask on diagonal tile
        #pragma unroll
        for (int kt = 0; kt < 4; ++kt)
          #pragma unroll
          for (int qi = 0; qi < 2; ++qi)
            #pragma unroll
            for (int t = 0; t < 4; ++t) {
              int kv = kv0 + kt * 16 + 4 * g + t;
              if (kv > q0w + qi * 16 + ql) sacc[kt][qi][t] = -1e30f;
            }
      }
      float bm0 = sacc[0][0][0], bm1 = sacc[0][1][0];
      #pragma unroll
      for (int kt = 0; kt < 4; ++kt)
        #pragma unroll
        for (int t = 0; t < 4; ++t) {
          bm0 = fmaxf(bm0, sacc[kt][0][t]);
          bm1 = fmaxf(bm1, sacc[kt][1][t]);
        }
      bm0 = fmaxf(bm0, __shfl_xor(bm0, 16)); bm0 = fmaxf(bm0, __shfl_xor(bm0, 32));
      bm1 = fmaxf(bm1, __shfl_xor(bm1, 16)); bm1 = fmaxf(bm1, __shfl_xor(bm1, 32));
      if (!__all(bm0 <= m0 + 8.f && bm1 <= m1 + 8.f)) {   // defer-max (T13, log2 units)
        float mn0 = fmaxf(m0, bm0), mn1 = fmaxf(m1, bm1);
        float a0 = EXP2(m0 - mn0), a1 = EXP2(m1 - mn1);
        m0 = mn0; m1 = mn1; l0 *= a0; l1 *= a1;
        #pragma unroll
        for (int dt = 0; dt < 4; ++dt)
          #pragma unroll
          for (int t = 0; t < 4; ++t) { oacc[dt][0][t] *= a0; oacc[dt][1][t] *= a1; }
      }
      float ps0 = 0.f, ps1 = 0.f;
      #pragma unroll
      for (int kt = 0; kt < 4; ++kt)
        #pragma unroll
        for (int t = 0; t < 4; ++t) {
          float e0 = EXP2(sacc[kt][0][t] - m0); sacc[kt][0][t] = e0; ps0 += e0;
          float e1 = EXP2(sacc[kt][1][t] - m1); sacc[kt][1][t] = e1; ps1 += e1;
        }
      ps0 += __shfl_xor(ps0, 16); ps0 += __shfl_xor(ps0, 32);
      ps1 += __shfl_xor(ps1, 16); ps1 += __shfl_xor(ps1, 32);
      l0 += ps0; l1 += ps1;

      #pragma unroll
      for (int qi = 0; qi < 2; ++qi)
        #pragma unroll
        for (int kt = 0; kt < 4; ++kt) {
          uint2 w;
          w.x = (unsigned)f2bf(sacc[kt][qi][0]) | ((unsigned)f2bf(sacc[kt][qi][1]) << 16);
          w.y = (unsigned)f2bf(sacc[kt][qi][2]) | ((unsigned)f2bf(sacc[kt][qi][3]) << 16);
          *(uint2*)(pbase + qi * 2048 + ((ql * 128 + kt * 32 + g * 8) ^ swz)) = w;
        }
      short8 pf[2][2];
      #pragma unroll
      for (int qi = 0; qi < 2; ++qi)
        #pragma unroll
        for (int c = 0; c < 2; ++c)
          pf[qi][c] = *(const short8*)(pbase + qi * 2048 + ((ql * 128 + c * 64 + g * 16) ^ swz));
      __builtin_amdgcn_s_setprio(1);
      #pragma unroll
      for (int dt = 0; dt < 4; ++dt)
        #pragma unroll
        for (int c = 0; c < 2; ++c)
          #pragma unroll
          for (int qi = 0; qi < 2; ++qi)
            oacc[dt][qi] = __builtin_amdgcn_mfma_f32_16x16x32_bf16(vf[dt][c], pf[qi][c],
                                                                   oacc[dt][qi], 0, 0, 0);
      __builtin_amdgcn_s_setprio(0);
      if (kb + 1 < nkb) {
        #pragma unroll
        for (int kt = 0; kt < 4; ++kt)
          #pragma unroll
          for (int s = 0; s < 2; ++s) kf[kt][s] = kfn[kt][s];
      }
    }

    const float inv0 = 1.f / l0, inv1 = 1.f / l1;
    #pragma unroll
    for (int qi = 0; qi < 2; ++qi) {
      const float inv = qi ? inv1 : inv0;
      unsigned short* ao = AO + (size_t)(b * 2048 + q0w + qi * 16 + ql) * 2048 + h * 64;
      #pragma unroll
      for (int dt = 0; dt < 4; ++dt) {
        ushort4 pk;
        pk.x = f2bf(oacc[dt][qi][0] * inv); pk.y = f2bf(oacc[dt][qi][1] * inv);
        pk.z = f2bf(oacc[dt][qi][2] * inv); pk.w = f2bf(oacc[dt][qi][3] * inv);
        *(ushort4*)&ao[dt * 16 + 4 * g] = pk;
      }
    }
  }
}

extern "C" void kernel_launch(void* const* d_in, const int* in_sizes, int n_in,
                              void* d_out, int out_size, void* d_ws, size_t ws_size,
                              hipStream_t stream) {
  const float* x    = (const float*)d_in[0];
  const float* freq = (const float*)d_in[1];
  const float* Wq = (const float*)d_in[4];
  const float* Wk = (const float*)d_in[5];
  const float* Wv = (const float*)d_in[6];
  const float* Wo = (const float*)d_in[7];
  float* out = (float*)d_out;

  char* ws = (char*)d_ws;
  unsigned short* xb   = (unsigned short*)(ws);             // [4096][2048] bf16, 16.78 MB
  unsigned short* Wqkv = (unsigned short*)(ws + 16777216);  // [3072][2048] bf16, 12.58 MB
  unsigned short* Qb   = (unsigned short*)(ws + 29360128);  // [4096][2048] bf16 (pre-scaled)
  unsigned short* Kb   = (unsigned short*)(ws + 46137344);  // [4096][512]  bf16
  unsigned short* Vt   = (unsigned short*)(ws + 50331648);  // [2][8][64][2048]
  unsigned short* AO   = xb;                                // alias: x dead after QKV GEMM
  unsigned short* Wot  = Wqkv;                              // alias: Wqkv dead after QKV GEMM

  cast_x_kernel<<<8192, 256, 0, stream>>>(x, xb, 2097152);
  transpose_cast<<<dim3(64, 64), 256, 0, stream>>>(Wq, Wqkv, 2048);
  transpose_cast<<<dim3(16, 64), 256, 0, stream>>>(Wk, Wqkv + (size_t)2048 * 2048, 512);
  transpose_cast<<<dim3(16, 64), 256, 0, stream>>>(Wv, Wqkv + (size_t)2560 * 2048, 512);
  gemm128<<<dim3(32, 24), 256, 0, stream>>>(xb, Wqkv, freq, nullptr, Qb, Kb, Vt, 1);
  transpose_cast<<<dim3(64, 64), 256, 0, stream>>>(Wo, Wot, 2048);
  attn_kernel<<<512, 256, 0, stream>>>(Qb, Kb, Vt, AO);
  gemm128<<<dim3(32, 16), 256, 0, stream>>>(AO, Wot, freq, out, nullptr, nullptr, nullptr, 0);
}